// Round 8
// baseline (358.028 us; speedup 1.0000x reference)
//
#include <hip/hip_runtime.h>
#include <hip/hip_fp16.h>

#define DIM_IN   8192
#define DIM_OUT  8192
#define FAN      16
#define BATCH    1024
#define NNZ      (DIM_IN * FAN)
#define ROUT     32

// ---------------- build: range-scan, LDS atomics only (proven R3-R7) -------
__global__ __launch_bounds__(1024)
void build_scan_kernel(const int* __restrict__ pre,
                       const int* __restrict__ post,
                       int* __restrict__ idx) {
    __shared__ int cnt[ROUT];
    __shared__ int sidx[ROUT * FAN];
    const int t  = threadIdx.x;
    const int j0 = blockIdx.x * ROUT;

    if (t < ROUT) cnt[t] = 0;
    __syncthreads();

    for (int base = 0; base < NNZ; base += 4096) {
        const int e0 = base + t;
        const int p0 = post[e0];
        const int p1 = post[e0 + 1024];
        const int p2 = post[e0 + 2048];
        const int p3 = post[e0 + 3072];

        const unsigned r0 = (unsigned)(p0 - j0);
        const unsigned r1 = (unsigned)(p1 - j0);
        const unsigned r2 = (unsigned)(p2 - j0);
        const unsigned r3 = (unsigned)(p3 - j0);

        if (r0 < ROUT) { int s = atomicAdd(&cnt[r0], 1); if (s < FAN) sidx[r0 * FAN + s] = pre[e0]; }
        if (r1 < ROUT) { int s = atomicAdd(&cnt[r1], 1); if (s < FAN) sidx[r1 * FAN + s] = pre[e0 + 1024]; }
        if (r2 < ROUT) { int s = atomicAdd(&cnt[r2], 1); if (s < FAN) sidx[r2 * FAN + s] = pre[e0 + 2048]; }
        if (r3 < ROUT) { int s = atomicAdd(&cnt[r3], 1); if (s < FAN) sidx[r3 * FAN + s] = pre[e0 + 3072]; }
    }
    __syncthreads();

    if (t < ROUT * FAN) idx[(size_t)j0 * FAN + t] = sidx[t];
}

// ---------------- transpose x f32 [B][D] -> xt f16 [D][B], AMPLIFIED x8 ----
__global__ __launch_bounds__(256)
void transpose_amp_kernel(const float* __restrict__ x, __half* __restrict__ xt) {
    const int t  = threadIdx.x;
    const int it = blockIdx.x & 127;
    const int bt = blockIdx.x >> 7;
    const int i0 = it * 64, b0 = bt * 64;
    const int bq = t & 15;
    const int iq = t >> 4;

    for (int rep = 0; rep < 8; ++rep) {
        float4 m[4];
#pragma unroll
        for (int r = 0; r < 4; ++r)
            m[r] = *reinterpret_cast<const float4*>(
                x + (size_t)(b0 + bq * 4 + r) * DIM_IN + i0 + iq * 4);

#pragma unroll
        for (int e = 0; e < 4; ++e) {
            __half2 lo, hi;
            lo.x = __float2half(((const float*)&m[0])[e]);
            lo.y = __float2half(((const float*)&m[1])[e]);
            hi.x = __float2half(((const float*)&m[2])[e]);
            hi.y = __float2half(((const float*)&m[3])[e]);
            uint2 w;
            w.x = *reinterpret_cast<unsigned*>(&lo);
            w.y = *reinterpret_cast<unsigned*>(&hi);
            *reinterpret_cast<uint2*>(xt + (size_t)(i0 + iq * 4 + e) * BATCH + b0 + bq * 4) = w;
        }
        asm volatile("" ::: "memory");   // defeat cross-rep load CSE
    }
}

// ---------------- SpMM v2 (BT=128 XCD-pinned), AMPLIFIED x8 ----------------
#define JT 64
#define BT 128
__global__ __launch_bounds__(1024)
void spmm2_amp_kernel(const __half* __restrict__ xt,
                      const int*    __restrict__ idx,
                      float*        __restrict__ y) {
    __shared__ int sidx[JT * FAN];
    const int bid   = blockIdx.x;
    const int btile = bid & 7;
    const int jtile = bid >> 3;
    const int j0 = jtile * JT;
    const int b0 = btile * BT;
    const int t  = threadIdx.x;

    sidx[t] = idx[(size_t)j0 * FAN + t];
    __syncthreads();

    const int jj = t >> 4;
    const int bb = t & 15;
    const __half* base = xt + b0 + bb * 8;

    for (int rep = 0; rep < 8; ++rep) {
        const __half2 z = __float2half2_rn(0.f);
        __half2 aP0 = z, aP1 = z, aP2 = z, aP3 = z;
        __half2 aQ0 = z, aQ1 = z, aQ2 = z, aQ3 = z;

#pragma unroll
        for (int k = 0; k < FAN; k += 2) {
            const int iA = sidx[jj * FAN + k];
            const int iB = sidx[jj * FAN + k + 1];
            const uint4 uA = *reinterpret_cast<const uint4*>(base + (size_t)iA * BATCH);
            const uint4 uB = *reinterpret_cast<const uint4*>(base + (size_t)iB * BATCH);
            aP0 = __hadd2(aP0, *reinterpret_cast<const __half2*>(&uA.x));
            aP1 = __hadd2(aP1, *reinterpret_cast<const __half2*>(&uA.y));
            aP2 = __hadd2(aP2, *reinterpret_cast<const __half2*>(&uA.z));
            aP3 = __hadd2(aP3, *reinterpret_cast<const __half2*>(&uA.w));
            aQ0 = __hadd2(aQ0, *reinterpret_cast<const __half2*>(&uB.x));
            aQ1 = __hadd2(aQ1, *reinterpret_cast<const __half2*>(&uB.y));
            aQ2 = __hadd2(aQ2, *reinterpret_cast<const __half2*>(&uB.z));
            aQ3 = __hadd2(aQ3, *reinterpret_cast<const __half2*>(&uB.w));
        }

        float* yb = y + (size_t)(b0 + bb * 8) * DIM_OUT + j0 + jj;
        const __half2 P[4] = {aP0, aP1, aP2, aP3};
        const __half2 Q[4] = {aQ0, aQ1, aQ2, aQ3};
#pragma unroll
        for (int m = 0; m < 8; ++m) {
            const float vP = (m & 1) ? __high2float(P[m >> 1]) : __low2float(P[m >> 1]);
            const float vQ = (m & 1) ? __high2float(Q[m >> 1]) : __low2float(Q[m >> 1]);
            yb[(size_t)m * DIM_OUT] = 100.0f * (vP + vQ);
        }
        asm volatile("" ::: "memory");   // defeat cross-rep load CSE
    }
}

// ---------------- LDS gather (R4-proven), gather phase AMPLIFIED x4 --------
#define ROWS     8
#define BLOCK    1024
#define OSPLIT   2
#define OCHUNK   (DIM_OUT / OSPLIT)
#define LDS_BYTES (DIM_IN * ROWS * 2)
__global__ __launch_bounds__(BLOCK, 1)
void gather_amp_kernel(const float* __restrict__ x,
                       const int*   __restrict__ idx,
                       float*       __restrict__ y) {
    extern __shared__ __half ldsh[];
    const int t  = threadIdx.x;
    const int b0 = (blockIdx.x >> 1) * ROWS;
    const int j0 = (blockIdx.x & 1) * OCHUNK;

#pragma unroll
    for (int c = 0; c < DIM_IN / BLOCK; ++c) {
        const int i = t + c * BLOCK;
        uint4 w;
        __half2 h;
        h.x = __float2half(x[(size_t)(b0 + 0) * DIM_IN + i]);
        h.y = __float2half(x[(size_t)(b0 + 1) * DIM_IN + i]);
        w.x = *reinterpret_cast<unsigned*>(&h);
        h.x = __float2half(x[(size_t)(b0 + 2) * DIM_IN + i]);
        h.y = __float2half(x[(size_t)(b0 + 3) * DIM_IN + i]);
        w.y = *reinterpret_cast<unsigned*>(&h);
        h.x = __float2half(x[(size_t)(b0 + 4) * DIM_IN + i]);
        h.y = __float2half(x[(size_t)(b0 + 5) * DIM_IN + i]);
        w.z = *reinterpret_cast<unsigned*>(&h);
        h.x = __float2half(x[(size_t)(b0 + 6) * DIM_IN + i]);
        h.y = __float2half(x[(size_t)(b0 + 7) * DIM_IN + i]);
        w.w = *reinterpret_cast<unsigned*>(&h);
        *reinterpret_cast<uint4*>(&ldsh[(size_t)i * ROWS]) = w;
    }
    __syncthreads();

    for (int rep = 0; rep < 4; ++rep) {
#pragma unroll
        for (int o = 0; o < OCHUNK / BLOCK; ++o) {
            const int j = j0 + t + o * BLOCK;
            const int4* ip = reinterpret_cast<const int4*>(idx + (size_t)j * FAN);
            int4 i0 = ip[0];
            int4 i1 = ip[1];
            int4 i2 = ip[2];
            int4 i3 = ip[3];

            float a0=0,a1=0,a2=0,a3=0,a4=0,a5=0,a6=0,a7=0;
            auto accum = [&](int i) {
                const uint4 u = *reinterpret_cast<const uint4*>(&ldsh[(size_t)i * ROWS]);
                float2 f;
                f = __half22float2(*reinterpret_cast<const __half2*>(&u.x)); a0 += f.x; a1 += f.y;
                f = __half22float2(*reinterpret_cast<const __half2*>(&u.y)); a2 += f.x; a3 += f.y;
                f = __half22float2(*reinterpret_cast<const __half2*>(&u.z)); a4 += f.x; a5 += f.y;
                f = __half22float2(*reinterpret_cast<const __half2*>(&u.w)); a6 += f.x; a7 += f.y;
            };
            accum(i0.x); accum(i0.y); accum(i0.z); accum(i0.w);
            accum(i1.x); accum(i1.y); accum(i1.z); accum(i1.w);
            accum(i2.x); accum(i2.y); accum(i2.z); accum(i2.w);
            accum(i3.x); accum(i3.y); accum(i3.z); accum(i3.w);

            y[(size_t)(b0 + 0) * DIM_OUT + j] = 100.0f * a0;
            y[(size_t)(b0 + 1) * DIM_OUT + j] = 100.0f * a1;
            y[(size_t)(b0 + 2) * DIM_OUT + j] = 100.0f * a2;
            y[(size_t)(b0 + 3) * DIM_OUT + j] = 100.0f * a3;
            y[(size_t)(b0 + 4) * DIM_OUT + j] = 100.0f * a4;
            y[(size_t)(b0 + 5) * DIM_OUT + j] = 100.0f * a5;
            y[(size_t)(b0 + 6) * DIM_OUT + j] = 100.0f * a6;
            y[(size_t)(b0 + 7) * DIM_OUT + j] = 100.0f * a7;
        }
        asm volatile("" ::: "memory");   // defeat cross-rep load CSE
    }
}

// ---------------- launch: A/B instrumentation round ------------------------
extern "C" void kernel_launch(void* const* d_in, const int* in_sizes, int n_in,
                              void* d_out, int out_size, void* d_ws, size_t ws_size,
                              hipStream_t stream) {
    const float* x    = (const float*)d_in[0];
    const int*   pre  = (const int*)d_in[1];
    const int*   post = (const int*)d_in[2];
    float*       y    = (float*)d_out;

    const size_t xt_bytes  = (size_t)DIM_IN * BATCH * sizeof(__half); // 16 MB
    const size_t idx_bytes = (size_t)NNZ * sizeof(int);               // 512 KB

    hipFuncSetAttribute((const void*)gather_amp_kernel,
                        hipFuncAttributeMaxDynamicSharedMemorySize, LDS_BYTES);

    if (ws_size >= xt_bytes + idx_bytes) {
        __half* xt  = (__half*)d_ws;
        int*    idx = (int*)((char*)d_ws + xt_bytes);

        build_scan_kernel<<<DIM_OUT / ROUT, 1024, 0, stream>>>(pre, post, idx);
        transpose_amp_kernel<<<(DIM_IN / 64) * (BATCH / 64), 256, 0, stream>>>(x, xt);
        spmm2_amp_kernel<<<(DIM_OUT / JT) * (BATCH / BT), 1024, 0, stream>>>(xt, idx, y);
        // gather path LAST: final y = R4-proven result
        gather_amp_kernel<<<(BATCH / ROWS) * OSPLIT, BLOCK, LDS_BYTES, stream>>>(x, idx, y);
    } else {
        int* idx = (int*)d_ws;
        build_scan_kernel<<<DIM_OUT / ROUT, 1024, 0, stream>>>(pre, post, idx);
        gather_amp_kernel<<<(BATCH / ROWS) * OSPLIT, BLOCK, LDS_BYTES, stream>>>(x, idx, y);
    }
}

// Round 9
// 134.199 us; speedup vs baseline: 2.6679x; 2.6679x over previous
//
#include <hip/hip_runtime.h>
#include <hip/hip_fp16.h>

#define DIM_IN   8192
#define DIM_OUT  8192
#define FAN      16
#define BATCH    1024
#define NNZ      (DIM_IN * FAN)
#define ROUT     32

// ---------------- build: range-scan, LDS atomics only (proven R3-R8) -------
__global__ __launch_bounds__(1024)
void build_scan_kernel(const int* __restrict__ pre,
                       const int* __restrict__ post,
                       int* __restrict__ idx) {
    __shared__ int cnt[ROUT];
    __shared__ int sidx[ROUT * FAN];
    const int t  = threadIdx.x;
    const int j0 = blockIdx.x * ROUT;

    if (t < ROUT) cnt[t] = 0;
    __syncthreads();

    for (int base = 0; base < NNZ; base += 4096) {
        const int e0 = base + t;
        const int p0 = post[e0];
        const int p1 = post[e0 + 1024];
        const int p2 = post[e0 + 2048];
        const int p3 = post[e0 + 3072];

        const unsigned r0 = (unsigned)(p0 - j0);
        const unsigned r1 = (unsigned)(p1 - j0);
        const unsigned r2 = (unsigned)(p2 - j0);
        const unsigned r3 = (unsigned)(p3 - j0);

        if (r0 < ROUT) { int s = atomicAdd(&cnt[r0], 1); if (s < FAN) sidx[r0 * FAN + s] = pre[e0]; }
        if (r1 < ROUT) { int s = atomicAdd(&cnt[r1], 1); if (s < FAN) sidx[r1 * FAN + s] = pre[e0 + 1024]; }
        if (r2 < ROUT) { int s = atomicAdd(&cnt[r2], 1); if (s < FAN) sidx[r2 * FAN + s] = pre[e0 + 2048]; }
        if (r3 < ROUT) { int s = atomicAdd(&cnt[r3], 1); if (s < FAN) sidx[r3 * FAN + s] = pre[e0 + 3072]; }
    }
    __syncthreads();

    if (t < ROUT * FAN) idx[(size_t)j0 * FAN + t] = sidx[t];
}

// ---------------- transpose: x f32 [B][D] -> xt f16 [D][B] (proven R5) -----
__global__ __launch_bounds__(256)
void transpose_kernel(const float* __restrict__ x, __half* __restrict__ xt) {
    const int t  = threadIdx.x;
    const int it = blockIdx.x & 127;
    const int bt = blockIdx.x >> 7;
    const int i0 = it * 64, b0 = bt * 64;
    const int bq = t & 15;
    const int iq = t >> 4;

    float4 m[4];
#pragma unroll
    for (int r = 0; r < 4; ++r)
        m[r] = *reinterpret_cast<const float4*>(
            x + (size_t)(b0 + bq * 4 + r) * DIM_IN + i0 + iq * 4);

#pragma unroll
    for (int e = 0; e < 4; ++e) {
        __half2 lo, hi;
        lo.x = __float2half(((const float*)&m[0])[e]);
        lo.y = __float2half(((const float*)&m[1])[e]);
        hi.x = __float2half(((const float*)&m[2])[e]);
        hi.y = __float2half(((const float*)&m[3])[e]);
        uint2 w;
        w.x = *reinterpret_cast<unsigned*>(&lo);
        w.y = *reinterpret_cast<unsigned*>(&hi);
        *reinterpret_cast<uint2*>(xt + (size_t)(i0 + iq * 4 + e) * BATCH + b0 + bq * 4) = w;
    }
}

// ---------------- SpMM v3 ---------------------------------------------------
// Block = 32 outputs x 128 batch, 256 threads; thread = 1 output x 16 batch
// (32B contiguous per random index). btile = bid&7 pins a 2MB xt slice per
// XCD (L2-resident; FETCH_SIZE ~10MB/8 passes proved residency in R8).
// Levers vs spmm2 (25us/pass): nontemporal y stores (stop y write-allocate
// evicting the xt slice), 24 waves/CU occupancy, 8 loads in flight per wave.
#define JT3 32
#define BT3 128
__global__ __launch_bounds__(256, 6)
void spmm3_kernel(const __half* __restrict__ xt,
                  const int*    __restrict__ idx,
                  float*        __restrict__ y) {
    __shared__ int sidx[JT3 * FAN];      // 2 KB
    const int bid   = blockIdx.x;
    const int btile = bid & 7;           // XCD id (round-robin dispatch)
    const int jtile = bid >> 3;          // 0..255
    const int j0 = jtile * JT3;
    const int b0 = btile * BT3;
    const int t  = threadIdx.x;

    sidx[t]       = idx[(size_t)j0 * FAN + t];
    sidx[t + 256] = idx[(size_t)j0 * FAN + t + 256];
    __syncthreads();

    const int jj = t >> 3;               // 0..31 (output)
    const int bb = t & 7;                // 0..7  (16 batch each)
    const __half* base = xt + b0 + bb * 16;

    const __half2 z = __float2half2_rn(0.f);
    __half2 accP[8] = {z, z, z, z, z, z, z, z};
    __half2 accQ[8] = {z, z, z, z, z, z, z, z};

#pragma unroll
    for (int r = 0; r < 4; ++r) {
        // issue all 8 loads (4 edges x 32B) before any adds
        uint4 u[8];
#pragma unroll
        for (int e = 0; e < 4; ++e) {
            const int i = sidx[jj * FAN + r * 4 + e];
            const uint4* p = reinterpret_cast<const uint4*>(base + (size_t)i * BATCH);
            u[2 * e]     = p[0];
            u[2 * e + 1] = p[1];
        }
#pragma unroll
        for (int e = 0; e < 4; ++e) {
#pragma unroll
            for (int q = 0; q < 4; ++q) {
                const __half2 lo = *reinterpret_cast<const __half2*>(&((const unsigned*)&u[2 * e])[q]);
                const __half2 hi = *reinterpret_cast<const __half2*>(&((const unsigned*)&u[2 * e + 1])[q]);
                if (r < 2) {             // r unrolled -> compile-time select
                    accP[q]     = __hadd2(accP[q], lo);
                    accP[q + 4] = __hadd2(accP[q + 4], hi);
                } else {
                    accQ[q]     = __hadd2(accQ[q], lo);
                    accQ[q + 4] = __hadd2(accQ[q + 4], hi);
                }
            }
        }
    }

    float* yb = y + (size_t)(b0 + bb * 16) * DIM_OUT + j0 + jj;
#pragma unroll
    for (int m = 0; m < 16; ++m) {
        const int h = m >> 1;
        const float vP = (m & 1) ? __high2float(accP[h]) : __low2float(accP[h]);
        const float vQ = (m & 1) ? __high2float(accQ[h]) : __low2float(accQ[h]);
        __builtin_nontemporal_store(100.0f * (vP + vQ), &yb[(size_t)m * DIM_OUT]);
    }
}

// ---------------- fallback (proven R4 path, small ws) ----------------------
#define ROWS     8
#define BLOCK    1024
#define OSPLIT   2
#define OCHUNK   (DIM_OUT / OSPLIT)
#define LDS_BYTES (DIM_IN * ROWS * 2)
__global__ __launch_bounds__(BLOCK, 1)
void gather_kernel(const float* __restrict__ x,
                   const int*   __restrict__ idx,
                   float*       __restrict__ y) {
    extern __shared__ __half ldsh[];
    const int t  = threadIdx.x;
    const int b0 = (blockIdx.x >> 1) * ROWS;
    const int j0 = (blockIdx.x & 1) * OCHUNK;

#pragma unroll
    for (int c = 0; c < DIM_IN / BLOCK; ++c) {
        const int i = t + c * BLOCK;
        uint4 w;
        __half2 h;
        h.x = __float2half(x[(size_t)(b0 + 0) * DIM_IN + i]);
        h.y = __float2half(x[(size_t)(b0 + 1) * DIM_IN + i]);
        w.x = *reinterpret_cast<unsigned*>(&h);
        h.x = __float2half(x[(size_t)(b0 + 2) * DIM_IN + i]);
        h.y = __float2half(x[(size_t)(b0 + 3) * DIM_IN + i]);
        w.y = *reinterpret_cast<unsigned*>(&h);
        h.x = __float2half(x[(size_t)(b0 + 4) * DIM_IN + i]);
        h.y = __float2half(x[(size_t)(b0 + 5) * DIM_IN + i]);
        w.z = *reinterpret_cast<unsigned*>(&h);
        h.x = __float2half(x[(size_t)(b0 + 6) * DIM_IN + i]);
        h.y = __float2half(x[(size_t)(b0 + 7) * DIM_IN + i]);
        w.w = *reinterpret_cast<unsigned*>(&h);
        *reinterpret_cast<uint4*>(&ldsh[(size_t)i * ROWS]) = w;
    }
    __syncthreads();

#pragma unroll
    for (int o = 0; o < OCHUNK / BLOCK; ++o) {
        const int j = j0 + t + o * BLOCK;
        const int4* ip = reinterpret_cast<const int4*>(idx + (size_t)j * FAN);
        int4 i0 = ip[0];
        int4 i1 = ip[1];
        int4 i2 = ip[2];
        int4 i3 = ip[3];

        float a0=0,a1=0,a2=0,a3=0,a4=0,a5=0,a6=0,a7=0;
        auto accum = [&](int i) {
            const uint4 u = *reinterpret_cast<const uint4*>(&ldsh[(size_t)i * ROWS]);
            float2 f;
            f = __half22float2(*reinterpret_cast<const __half2*>(&u.x)); a0 += f.x; a1 += f.y;
            f = __half22float2(*reinterpret_cast<const __half2*>(&u.y)); a2 += f.x; a3 += f.y;
            f = __half22float2(*reinterpret_cast<const __half2*>(&u.z)); a4 += f.x; a5 += f.y;
            f = __half22float2(*reinterpret_cast<const __half2*>(&u.w)); a6 += f.x; a7 += f.y;
        };
        accum(i0.x); accum(i0.y); accum(i0.z); accum(i0.w);
        accum(i1.x); accum(i1.y); accum(i1.z); accum(i1.w);
        accum(i2.x); accum(i2.y); accum(i2.z); accum(i2.w);
        accum(i3.x); accum(i3.y); accum(i3.z); accum(i3.w);

        y[(size_t)(b0 + 0) * DIM_OUT + j] = 100.0f * a0;
        y[(size_t)(b0 + 1) * DIM_OUT + j] = 100.0f * a1;
        y[(size_t)(b0 + 2) * DIM_OUT + j] = 100.0f * a2;
        y[(size_t)(b0 + 3) * DIM_OUT + j] = 100.0f * a3;
        y[(size_t)(b0 + 4) * DIM_OUT + j] = 100.0f * a4;
        y[(size_t)(b0 + 5) * DIM_OUT + j] = 100.0f * a5;
        y[(size_t)(b0 + 6) * DIM_OUT + j] = 100.0f * a6;
        y[(size_t)(b0 + 7) * DIM_OUT + j] = 100.0f * a7;
    }
}

// ---------------- launch ---------------------------------------------------
extern "C" void kernel_launch(void* const* d_in, const int* in_sizes, int n_in,
                              void* d_out, int out_size, void* d_ws, size_t ws_size,
                              hipStream_t stream) {
    const float* x    = (const float*)d_in[0];
    const int*   pre  = (const int*)d_in[1];
    const int*   post = (const int*)d_in[2];
    float*       y    = (float*)d_out;

    const size_t xt_bytes  = (size_t)DIM_IN * BATCH * sizeof(__half); // 16 MB
    const size_t idx_bytes = (size_t)NNZ * sizeof(int);               // 512 KB

    if (ws_size >= xt_bytes + idx_bytes) {
        __half* xt  = (__half*)d_ws;
        int*    idx = (int*)((char*)d_ws + xt_bytes);

        build_scan_kernel<<<DIM_OUT / ROUT, 1024, 0, stream>>>(pre, post, idx);
        transpose_kernel<<<(DIM_IN / 64) * (BATCH / 64), 256, 0, stream>>>(x, xt);
        spmm3_kernel<<<(DIM_OUT / JT3) * (BATCH / BT3), 256, 0, stream>>>(xt, idx, y);
    } else {
        int* idx = (int*)d_ws;
        hipFuncSetAttribute((const void*)gather_kernel,
                            hipFuncAttributeMaxDynamicSharedMemorySize, LDS_BYTES);
        build_scan_kernel<<<DIM_OUT / ROUT, 1024, 0, stream>>>(pre, post, idx);
        gather_kernel<<<(BATCH / ROWS) * OSPLIT, BLOCK, LDS_BYTES, stream>>>(x, idx, y);
    }
}

// Round 10
// 132.342 us; speedup vs baseline: 2.7053x; 1.0140x over previous
//
#include <hip/hip_runtime.h>
#include <hip/hip_fp16.h>

#define DIM_IN   8192
#define DIM_OUT  8192
#define FAN      16
#define BATCH    1024
#define NNZ      (DIM_IN * FAN)
#define ROUT     64                      // outputs owned per build block

// ---------------- build: range-scan, LDS atomics only ----------------------
// Block b owns outputs [b*ROUT,(b+1)*ROUT). Scans the edge list (coalesced,
// 4x unrolled), claims in-range edges via LDS atomicAdd, writes ROUTx16 ints
// coalesced. 128 blocks x 512KB post reads = 65MB L2/L3 traffic (~3us).
__global__ __launch_bounds__(1024)
void build_scan_kernel(const int* __restrict__ pre,
                       const int* __restrict__ post,
                       int* __restrict__ idx) {
    __shared__ int cnt[ROUT];
    __shared__ int sidx[ROUT * FAN];     // 4 KB
    const int t  = threadIdx.x;
    const int j0 = blockIdx.x * ROUT;

    if (t < ROUT) cnt[t] = 0;
    __syncthreads();

    for (int base = 0; base < NNZ; base += 4096) {
        const int e0 = base + t;
        const int p0 = post[e0];
        const int p1 = post[e0 + 1024];
        const int p2 = post[e0 + 2048];
        const int p3 = post[e0 + 3072];

        const unsigned r0 = (unsigned)(p0 - j0);
        const unsigned r1 = (unsigned)(p1 - j0);
        const unsigned r2 = (unsigned)(p2 - j0);
        const unsigned r3 = (unsigned)(p3 - j0);

        if (r0 < ROUT) { int s = atomicAdd(&cnt[r0], 1); if (s < FAN) sidx[r0 * FAN + s] = pre[e0]; }
        if (r1 < ROUT) { int s = atomicAdd(&cnt[r1], 1); if (s < FAN) sidx[r1 * FAN + s] = pre[e0 + 1024]; }
        if (r2 < ROUT) { int s = atomicAdd(&cnt[r2], 1); if (s < FAN) sidx[r2 * FAN + s] = pre[e0 + 2048]; }
        if (r3 < ROUT) { int s = atomicAdd(&cnt[r3], 1); if (s < FAN) sidx[r3 * FAN + s] = pre[e0 + 3072]; }
    }
    __syncthreads();

    idx[(size_t)j0 * FAN + t] = sidx[t];             // ROUT*FAN == 1024
}

// ---------------- main gather kernel (R4-proven) ---------------------------
// 8 batch rows staged as fp16, interleaved: ldsh[i*8 + r] = (half)x[b0+r][i].
// One ds_read_b128 per edge serves 8 batch rows. fp32 accumulation.
// 256 blocks = 128 row-groups x 2 output-halves -> 1 block/CU.
// Floor: 1024 wave-b128/CU x ~62cyc (random-cell conflict tax) ~= 26us.
#define ROWS     8
#define BLOCK    1024
#define OSPLIT   2
#define OCHUNK   (DIM_OUT / OSPLIT)
#define LDS_BYTES (DIM_IN * ROWS * 2)    // 128 KiB
__global__ __launch_bounds__(BLOCK, 1)
void gather_kernel(const float* __restrict__ x,
                   const int*   __restrict__ idx,
                   float*       __restrict__ y) {
    extern __shared__ __half ldsh[];
    const int t  = threadIdx.x;
    const int b0 = (blockIdx.x >> 1) * ROWS;
    const int j0 = (blockIdx.x & 1) * OCHUNK;

#pragma unroll
    for (int c = 0; c < DIM_IN / BLOCK; ++c) {
        const int i = t + c * BLOCK;
        uint4 w;
        __half2 h;
        h.x = __float2half(__builtin_nontemporal_load(&x[(size_t)(b0 + 0) * DIM_IN + i]));
        h.y = __float2half(__builtin_nontemporal_load(&x[(size_t)(b0 + 1) * DIM_IN + i]));
        w.x = *reinterpret_cast<unsigned*>(&h);
        h.x = __float2half(__builtin_nontemporal_load(&x[(size_t)(b0 + 2) * DIM_IN + i]));
        h.y = __float2half(__builtin_nontemporal_load(&x[(size_t)(b0 + 3) * DIM_IN + i]));
        w.y = *reinterpret_cast<unsigned*>(&h);
        h.x = __float2half(__builtin_nontemporal_load(&x[(size_t)(b0 + 4) * DIM_IN + i]));
        h.y = __float2half(__builtin_nontemporal_load(&x[(size_t)(b0 + 5) * DIM_IN + i]));
        w.z = *reinterpret_cast<unsigned*>(&h);
        h.x = __float2half(__builtin_nontemporal_load(&x[(size_t)(b0 + 6) * DIM_IN + i]));
        h.y = __float2half(__builtin_nontemporal_load(&x[(size_t)(b0 + 7) * DIM_IN + i]));
        w.w = *reinterpret_cast<unsigned*>(&h);
        *reinterpret_cast<uint4*>(&ldsh[(size_t)i * ROWS]) = w;
    }
    __syncthreads();

#pragma unroll
    for (int o = 0; o < OCHUNK / BLOCK; ++o) {
        const int j = j0 + t + o * BLOCK;
        const int4* ip = reinterpret_cast<const int4*>(idx + (size_t)j * FAN);
        int4 i0 = ip[0];
        int4 i1 = ip[1];
        int4 i2 = ip[2];
        int4 i3 = ip[3];

        float a0=0,a1=0,a2=0,a3=0,a4=0,a5=0,a6=0,a7=0;
        auto accum = [&](int i) {
            const uint4 u = *reinterpret_cast<const uint4*>(&ldsh[(size_t)i * ROWS]);
            float2 f;
            f = __half22float2(*reinterpret_cast<const __half2*>(&u.x)); a0 += f.x; a1 += f.y;
            f = __half22float2(*reinterpret_cast<const __half2*>(&u.y)); a2 += f.x; a3 += f.y;
            f = __half22float2(*reinterpret_cast<const __half2*>(&u.z)); a4 += f.x; a5 += f.y;
            f = __half22float2(*reinterpret_cast<const __half2*>(&u.w)); a6 += f.x; a7 += f.y;
        };
        accum(i0.x); accum(i0.y); accum(i0.z); accum(i0.w);
        accum(i1.x); accum(i1.y); accum(i1.z); accum(i1.w);
        accum(i2.x); accum(i2.y); accum(i2.z); accum(i2.w);
        accum(i3.x); accum(i3.y); accum(i3.z); accum(i3.w);

        // y is a 32MB write-once stream: nontemporal, skip L2 write-allocate
        __builtin_nontemporal_store(100.0f * a0, &y[(size_t)(b0 + 0) * DIM_OUT + j]);
        __builtin_nontemporal_store(100.0f * a1, &y[(size_t)(b0 + 1) * DIM_OUT + j]);
        __builtin_nontemporal_store(100.0f * a2, &y[(size_t)(b0 + 2) * DIM_OUT + j]);
        __builtin_nontemporal_store(100.0f * a3, &y[(size_t)(b0 + 3) * DIM_OUT + j]);
        __builtin_nontemporal_store(100.0f * a4, &y[(size_t)(b0 + 4) * DIM_OUT + j]);
        __builtin_nontemporal_store(100.0f * a5, &y[(size_t)(b0 + 5) * DIM_OUT + j]);
        __builtin_nontemporal_store(100.0f * a6, &y[(size_t)(b0 + 6) * DIM_OUT + j]);
        __builtin_nontemporal_store(100.0f * a7, &y[(size_t)(b0 + 7) * DIM_OUT + j]);
    }
}

// ---------------- launch ---------------------------------------------------
extern "C" void kernel_launch(void* const* d_in, const int* in_sizes, int n_in,
                              void* d_out, int out_size, void* d_ws, size_t ws_size,
                              hipStream_t stream) {
    const float* x    = (const float*)d_in[0];
    const int*   pre  = (const int*)d_in[1];
    const int*   post = (const int*)d_in[2];
    float*       y    = (float*)d_out;
    int*         idx  = (int*)d_ws;      // NNZ ints

    hipFuncSetAttribute((const void*)gather_kernel,
                        hipFuncAttributeMaxDynamicSharedMemorySize, LDS_BYTES);

    build_scan_kernel<<<DIM_OUT / ROUT, 1024, 0, stream>>>(pre, post, idx);
    gather_kernel<<<(BATCH / ROWS) * OSPLIT, BLOCK, LDS_BYTES, stream>>>(x, idx, y);
}